// Round 11
// baseline (495.827 us; speedup 1.0000x reference)
//
#include <hip/hip_runtime.h>
#include <math.h>

#define B_  32
#define L_  1024
#define D_  512
#define H_  8
#define G_  65
#define K_  16
#define DH_ 64
#define HG_  (H_ * G_)   // 520
#define HGP_ 576         // padded rows for p
#define BL_  (B_ * L_)   // 32768
#define NROW_ (B_ * H_ * G_)  // 16640

typedef _Float16 f16x8 __attribute__((ext_vector_type(8)));
typedef float f32x4 __attribute__((ext_vector_type(4)));

__device__ __forceinline__ unsigned int f2s(float f) {
  unsigned int u = __float_as_uint(f);
  return (u & 0x80000000u) ? ~u : (u | 0x80000000u);
}
__device__ __forceinline__ float s2f(unsigned int u) {
  return __uint_as_float((u & 0x80000000u) ? (u & 0x7FFFFFFFu) : ~u);
}
// fp16 2-plane split, flush-safe: both planes are normal-or-zero fp16 (lo is
// pre-scaled by 2^12). value ~= hi + lo*2^-12 with rel err ~2^-24.
__device__ __forceinline__ void split16(float v, _Float16* h, _Float16* l) {
  _Float16 h0 = (_Float16)v;
  float hf = (float)h0;
  if (fabsf(v) < 6.103515625e-05f) { h0 = (_Float16)0.f; hf = 0.f; }
  *h = h0;
  *l = (_Float16)((v - hf) * 4096.0f);
}
__device__ __forceinline__ void gload16(const void* g, void* l) {
  __builtin_amdgcn_global_load_lds(
      (const __attribute__((address_space(1))) unsigned int*)g,
      (__attribute__((address_space(3))) unsigned int*)l, 16, 0, 0);
}

// 1) t = log(relu(x)+1) -> fp16 hi + fp16 scaled-lo
__global__ void transform_split_kernel(const float* __restrict__ x,
                                       _Float16* __restrict__ th16,
                                       _Float16* __restrict__ tl16, int n4) {
  int i = blockIdx.x * blockDim.x + threadIdx.x;
  int stride = gridDim.x * blockDim.x;
  const float4* x4 = (const float4*)x;
  for (; i < n4; i += stride) {
    float4 a = x4[i];
    float t[4];
    t[0] = logf(fmaxf(a.x, 0.f) + 1.f);
    t[1] = logf(fmaxf(a.y, 0.f) + 1.f);
    t[2] = logf(fmaxf(a.z, 0.f) + 1.f);
    t[3] = logf(fmaxf(a.w, 0.f) + 1.f);
    _Float16 h[4], l[4];
#pragma unroll
    for (int j = 0; j < 4; ++j) split16(t[j], &h[j], &l[j]);
    *(ushort4*)&th16[i * 4] = *(ushort4*)h;
    *(ushort4*)&tl16[i * 4] = *(ushort4*)l;
  }
}

// 2) Wv -> Wv_T fp16 hi only (v path is precision-insensitive, r3/r4 evidence)
__global__ __launch_bounds__(256) void wvt_kernel(const float* __restrict__ Wv,
                                                  _Float16* __restrict__ wvt16) {
  int n = blockIdx.x;
  for (int k = threadIdx.x; k < 512; k += 256)
    wvt16[n * 512 + k] = (_Float16)Wv[(size_t)k * 512 + n];
}

// 3) q = target @ Wq + bq   [G,512] fp32
__global__ __launch_bounds__(256) void qproj_kernel(const float* __restrict__ target,
                                                    const float* __restrict__ Wq,
                                                    const float* __restrict__ bq,
                                                    float* __restrict__ q) {
  int g = blockIdx.x;
  int d = blockIdx.y * 256 + threadIdx.x;
  __shared__ float ts[512];
  for (int i = threadIdx.x; i < 512; i += 256) ts[i] = target[g * 512 + i];
  __syncthreads();
  float acc = bq[d];
  for (int c = 0; c < 512; ++c) acc += ts[c] * Wq[c * 512 + d];
  q[g * 512 + d] = acc;
}

// 4) p[hg][c] = sum_d Wk[c][h*64+d] * q[g][h*64+d], fp32 -> fp16 hi/lo planes.
//    rows 520..575 zeroed.
__global__ __launch_bounds__(256) void p_kernel(const float* __restrict__ q,
                                                const float* __restrict__ Wk,
                                                _Float16* __restrict__ ph16,
                                                _Float16* __restrict__ pl16) {
  int hg = blockIdx.x;
  int tid = threadIdx.x;
  if (hg >= HG_) {
    ph16[(size_t)hg * 512 + tid] = (_Float16)0.f;
    ph16[(size_t)hg * 512 + tid + 256] = (_Float16)0.f;
    pl16[(size_t)hg * 512 + tid] = (_Float16)0.f;
    pl16[(size_t)hg * 512 + tid + 256] = (_Float16)0.f;
    return;
  }
  int h = hg / G_, g = hg % G_;
  int lane = tid & 63, wid = tid >> 6;
  float qv = q[g * 512 + h * 64 + lane];
  for (int c = wid * 128; c < wid * 128 + 128; ++c) {
    float prod = Wk[(size_t)c * 512 + h * 64 + lane] * qv;
#pragma unroll
    for (int off = 32; off > 0; off >>= 1) prod += __shfl_xor(prod, off);
    if (lane == 0) {
      _Float16 hh, ll;
      split16(prod, &hh, &ll);
      ph16[(size_t)hg * 512 + c] = hh;
      pl16[(size_t)hg * 512 + c] = ll;
    }
  }
}

// 5) scores GEMM: S = p . t, fp16 2-plane / 3-product (rel err ~2^-24).
//    Double-buffered BK=32 one-barrier pipeline. __launch_bounds__(256,4):
//    4 blocks/CU so other blocks' waves fill each block's barrier drain
//    (r10 showed the loop is drain-latency-bound, not MFMA-bound).
//    M-tile 96 (grid.y=6), N-tile 128 (grid.x=256).
__global__ __launch_bounds__(256, 4) void scores_gemm_kernel(
    const _Float16* __restrict__ th16, const _Float16* __restrict__ tl16,
    const _Float16* __restrict__ ph16, const _Float16* __restrict__ pl16,
    float* __restrict__ scores) {
  // 2 bufs x 2 planes x [128 rows][32 k] fp16 = 2 x 16KB
  __shared__ char lds[32768];
  const int tid = threadIdx.x;
  const int lane = tid & 63;
  const int wid = tid >> 6;          // wave 0..3 -> n-subtile of 32 cols
  const int n0 = blockIdx.x * 128;
  const int m0 = blockIdx.y * 96;
  const int l16 = lane & 15;
  const int lg = lane >> 4;          // k-group 0..3 (8 elems each)

  f32x4 acc0[6][2], acc1[6][2];
#pragma unroll
  for (int i = 0; i < 6; ++i)
#pragma unroll
    for (int j = 0; j < 2; ++j) { acc0[i][j] = (f32x4)(0.f); acc1[i][j] = (f32x4)(0.f); }

  const int st_row = wid * 16 + (lane >> 2);
  const int st_s   = lane & 3;

#define STAGE_SC(buf, ks)                                                      \
  {                                                                            \
    _Pragma("unroll")                                                          \
    for (int it = 0; it < 2; ++it) {                                           \
      int row = it * 64 + st_row;                                              \
      size_t src = (size_t)(n0 + row) * 512 + (ks) * 32 +                      \
                   ((st_s ^ (row & 3)) << 3);                                  \
      char* dst = lds + (buf) * 16384 + it * 4096 + wid * 1024;                \
      gload16(th16 + src, dst);                                                \
      gload16(tl16 + src, dst + 8192);                                         \
    }                                                                          \
  }

  const size_t arow = (size_t)(m0 + l16) * 512 + lg * 8;

  STAGE_SC(0, 0);
  __syncthreads();

  for (int ks = 0; ks < 16; ++ks) {
    const int cur = ks & 1;
    // A fragments (p planes, L2-resident) first
    f16x8 Ah[6], Al[6];
#pragma unroll
    for (int fm = 0; fm < 6; ++fm) {
      size_t ao = arow + (size_t)fm * 16 * 512 + ks * 32;
      Ah[fm] = *(const f16x8*)(ph16 + ao);
      Al[fm] = *(const f16x8*)(pl16 + ao);
    }
    if (ks < 15) STAGE_SC(cur ^ 1, ks + 1);
    // B fragments from current LDS buffer
    f16x8 Bh[2], Bl[2];
#pragma unroll
    for (int fn = 0; fn < 2; ++fn) {
      int r = wid * 32 + fn * 16 + l16;
      int addr = cur * 16384 + r * 64 + ((lg ^ (r & 3)) << 4);
      Bh[fn] = *(const f16x8*)(lds + addr);
      Bl[fn] = *(const f16x8*)(lds + addr + 8192);
    }
#pragma unroll
    for (int fm = 0; fm < 6; ++fm) {
#pragma unroll
      for (int fn = 0; fn < 2; ++fn) {
        acc0[fm][fn] = __builtin_amdgcn_mfma_f32_16x16x32_f16(Ah[fm], Bh[fn], acc0[fm][fn], 0, 0, 0);
        acc1[fm][fn] = __builtin_amdgcn_mfma_f32_16x16x32_f16(Ah[fm], Bl[fn], acc1[fm][fn], 0, 0, 0);
        acc1[fm][fn] = __builtin_amdgcn_mfma_f32_16x16x32_f16(Al[fm], Bh[fn], acc1[fm][fn], 0, 0, 0);
      }
    }
    __syncthreads();
  }
#undef STAGE_SC

#pragma unroll
  for (int fm = 0; fm < 6; ++fm) {
    int hg0 = m0 + fm * 16 + ((lane >> 4) << 2);
#pragma unroll
    for (int fn = 0; fn < 2; ++fn) {
      int col = n0 + wid * 32 + fn * 16 + l16;
#pragma unroll
      for (int r = 0; r < 4; ++r) {
        int row = hg0 + r;
        if (row < HG_)
          scores[(size_t)row * BL_ + col] =
              acc0[fm][fn][r] + acc1[fm][fn][r] * 0.000244140625f;
      }
    }
  }
}

// 6) V GEMM: V[bl][n] = sum_c t[bl][c]*Wv[c][n] + bv[n], fp16 1-term
//    (v path precision-insensitive: r3/r4 bit-identical absmax evidence).
//    fp16 output. M-tile 128 (grid.x=256), N-tile 128 (grid.y=4).
__global__ __launch_bounds__(256, 2) void vgemm_kernel(
    const _Float16* __restrict__ th16, const _Float16* __restrict__ wvt16,
    const float* __restrict__ bv, _Float16* __restrict__ vout) {
  __shared__ char lds[16384];  // t_hi tile [128][64] fp16, slot-swizzled
  const int tid = threadIdx.x;
  const int lane = tid & 63;
  const int wid = tid >> 6;
  const int wave_m = wid >> 1;
  const int wave_n = wid & 1;
  const int m0 = blockIdx.x * 128;
  const int n0 = blockIdx.y * 128;

  f32x4 acc[4][4];
#pragma unroll
  for (int i = 0; i < 4; ++i)
#pragma unroll
    for (int j = 0; j < 4; ++j) acc[i][j] = (f32x4)(0.f);

  for (int k0 = 0; k0 < 512; k0 += 64) {
#pragma unroll
    for (int it = 0; it < 4; ++it) {
      int row = it * 32 + (tid >> 3);
      int j = tid & 7;
      size_t src = (size_t)(m0 + row) * 512 + k0 + ((j ^ (row & 7)) << 3);
      gload16(th16 + src, lds + it * 4096 + wid * 1024);
    }
    __syncthreads();
#pragma unroll
    for (int kh = 0; kh < 2; ++kh) {
      f16x8 Bv[4];
#pragma unroll
      for (int fn = 0; fn < 4; ++fn) {
        size_t bo = (size_t)(n0 + wave_n * 64 + fn * 16 + (lane & 15)) * 512 + k0 +
                    kh * 32 + ((lane >> 4) << 3);
        Bv[fn] = *(const f16x8*)(wvt16 + bo);
      }
#pragma unroll
      for (int fm = 0; fm < 4; ++fm) {
        int r = wave_m * 64 + fm * 16 + (lane & 15);
        int jl = kh * 4 + (lane >> 4);
        f16x8 Af = *(const f16x8*)(lds + r * 128 + ((jl ^ (r & 7)) << 4));
#pragma unroll
        for (int fn = 0; fn < 4; ++fn)
          acc[fm][fn] = __builtin_amdgcn_mfma_f32_16x16x32_f16(Af, Bv[fn], acc[fm][fn], 0, 0, 0);
      }
    }
    __syncthreads();
  }
#pragma unroll
  for (int fm = 0; fm < 4; ++fm) {
#pragma unroll
    for (int fn = 0; fn < 4; ++fn) {
      int col = n0 + wave_n * 64 + fn * 16 + (lane & 15);
      float bvv = bv[col];
#pragma unroll
      for (int r = 0; r < 4; ++r) {
        int row = m0 + wave_m * 64 + fm * 16 + ((lane >> 4) << 2) + r;
        vout[(size_t)row * 512 + col] = (_Float16)(acc[fm][fn][r] + bvv);
      }
    }
  }
}

// 7) one WAVE per row: top-16 with FUSED conv gather (v fp16); per-row
//    (min,max) to wmm[row] (no contended atomics).
__global__ __launch_bounds__(256) void topk_conv_kernel(const float* __restrict__ scores,
                                                        const _Float16* __restrict__ vbuf,
                                                        const float* __restrict__ conv_w,
                                                        const float* __restrict__ conv_b,
                                                        float* __restrict__ y,
                                                        float2* __restrict__ wmm) {
  int row = blockIdx.x * 4 + (threadIdx.x >> 6);  // (b*8+h)*65 + g
  int lane = threadIdx.x & 63;
  int g = row % G_;
  int bh = row / G_;
  int b = bh >> 3, h = bh & 7;
  const float* srow = scores + (size_t)(h * G_ + g) * BL_ + b * 1024;

  float s[16];
#pragma unroll
  for (int j = 0; j < 16; ++j) s[j] = srow[j * 64 + lane];  // coalesced

  const _Float16* vrow = vbuf + (size_t)b * 1024 * 512 + h * 64 + lane;
  float acc = conv_b[g];

#pragma unroll
  for (int r = 0; r < 16; ++r) {
    float bs = s[0];
    int bl = lane;
#pragma unroll
    for (int j = 1; j < 16; ++j) {
      bool t = s[j] > bs;
      bs = t ? s[j] : bs;
      bl = t ? j * 64 + lane : bl;
    }
#pragma unroll
    for (int off = 32; off > 0; off >>= 1) {
      float os = __shfl_xor(bs, off);
      int ol = __shfl_xor(bl, off);
      bool take = (os > bs) || (os == bs && ol < bl);
      bs = take ? os : bs;
      bl = take ? ol : bl;
    }
#pragma unroll
    for (int j = 0; j < 16; ++j)
      if (bl == j * 64 + lane) s[j] = -INFINITY;
    int sl = __builtin_amdgcn_readfirstlane(bl);
    acc += conv_w[g * 16 + r] * (float)vrow[(size_t)sl * 512];
  }

  y[(size_t)row * 64 + lane] = acc;

  float mn = acc, mx = acc;
#pragma unroll
  for (int off = 32; off > 0; off >>= 1) {
    float o = __shfl_xor(mn, off); mn = fminf(mn, o);
    float p = __shfl_xor(mx, off); mx = fmaxf(mx, p);
  }
  if (lane == 0) wmm[row] = make_float2(mn, mx);
}

// 7b) reduce 16640 per-row (min,max) pairs -> mm (130 uncontended atomics)
__global__ __launch_bounds__(256) void minmax_reduce_kernel(const float2* __restrict__ wmm,
                                                            unsigned int* __restrict__ minmax) {
  int i = blockIdx.x * 256 + threadIdx.x;
  float2 v = wmm[i];
  float mn = v.x, mx = v.y;
#pragma unroll
  for (int off = 32; off > 0; off >>= 1) {
    float o = __shfl_xor(mn, off); mn = fminf(mn, o);
    float p = __shfl_xor(mx, off); mx = fmaxf(mx, p);
  }
  __shared__ float smn[4], smx[4];
  int lane = threadIdx.x & 63, wid = threadIdx.x >> 6;
  if (lane == 0) { smn[wid] = mn; smx[wid] = mx; }
  __syncthreads();
  if (threadIdx.x == 0) {
    mn = fminf(fminf(smn[0], smn[1]), fminf(smn[2], smn[3]));
    mx = fmaxf(fmaxf(smx[0], smx[1]), fmaxf(smx[2], smx[3]));
    atomicMin(&minmax[0], f2s(mn));
    atomicMax(&minmax[1], f2s(mx));
  }
}

// 8) z[b,g,h*64+c] = exp((y[b,h,g,c]-mn)/(mx-mn))
__global__ void zprep_kernel(const float* __restrict__ y,
                             const unsigned int* __restrict__ minmax,
                             float* __restrict__ z) {
  int i = blockIdx.x * 256 + threadIdx.x;
  float mn = s2f(minmax[0]);
  float mx = s2f(minmax[1]);
  float inv = 1.f / (mx - mn);
  int c = i & 63;
  int t = i >> 6;
  int g = t % G_;
  int bh = t / G_;
  int b = bh >> 3, h = bh & 7;
  z[(size_t)(b * G_ + g) * 512 + h * 64 + c] = expf((y[i] - mn) * inv);
}

// 9) out = z @ Wo + bo ; M=2080 (guarded)
__global__ __launch_bounds__(256) void out_gemm_kernel(const float* __restrict__ z,
                                                       const float* __restrict__ Wo,
                                                       const float* __restrict__ bo,
                                                       float* __restrict__ out) {
  __shared__ float As[16][128];
  __shared__ float Bs[16][64];
  const int M = B_ * G_;
  int tid = threadIdx.x;
  int ty = tid >> 4, tx = tid & 15;
  int rowBase = blockIdx.y * 128;
  int colBase = blockIdx.x * 64;
  float acc[8][4] = {{0.f}};
  for (int k0 = 0; k0 < 512; k0 += 16) {
#pragma unroll
    for (int u = 0; u < 2; ++u) {
      int f = tid + u * 256;
      int m = f >> 2, kk4 = (f & 3) << 2;
      int row = rowBase + m;
      if (row > M - 1) row = M - 1;
      float4 a = *(const float4*)&z[(size_t)row * 512 + k0 + kk4];
      As[kk4 + 0][m] = a.x; As[kk4 + 1][m] = a.y;
      As[kk4 + 2][m] = a.z; As[kk4 + 3][m] = a.w;
    }
    {
      int r = tid >> 4, c4 = (tid & 15) << 2;
      *(float4*)&Bs[r][c4] = *(const float4*)&Wo[(size_t)(k0 + r) * 512 + colBase + c4];
    }
    __syncthreads();
#pragma unroll
    for (int kk = 0; kk < 16; ++kk) {
      float4 a0 = *(const float4*)&As[kk][ty * 8];
      float4 a1 = *(const float4*)&As[kk][ty * 8 + 4];
      float4 bvv = *(const float4*)&Bs[kk][tx * 4];
      float av[8] = {a0.x, a0.y, a0.z, a0.w, a1.x, a1.y, a1.z, a1.w};
      float bb[4] = {bvv.x, bvv.y, bvv.z, bvv.w};
#pragma unroll
      for (int i2 = 0; i2 < 8; ++i2)
#pragma unroll
        for (int j = 0; j < 4; ++j) acc[i2][j] += av[i2] * bb[j];
    }
    __syncthreads();
  }
#pragma unroll
  for (int i2 = 0; i2 < 8; ++i2) {
    int row = rowBase + ty * 8 + i2;
    if (row < M) {
#pragma unroll
      for (int j = 0; j < 4; ++j) {
        int col = colBase + tx * 4 + j;
        out[(size_t)row * 512 + col] = acc[i2][j] + bo[col];
      }
    }
  }
}

extern "C" void kernel_launch(void* const* d_in, const int* in_sizes, int n_in,
                              void* d_out, int out_size, void* d_ws, size_t ws_size,
                              hipStream_t stream) {
  const float* x      = (const float*)d_in[0];
  const float* Wq     = (const float*)d_in[1];
  const float* bq     = (const float*)d_in[2];
  const float* Wk     = (const float*)d_in[3];
  const float* bk     = (const float*)d_in[4];
  const float* Wv     = (const float*)d_in[5];
  const float* bv     = (const float*)d_in[6];
  const float* Wo     = (const float*)d_in[7];
  const float* bo     = (const float*)d_in[8];
  const float* target = (const float*)d_in[9];
  const float* conv_w = (const float*)d_in[10];
  const float* conv_b = (const float*)d_in[11];
  float* out = (float*)d_out;
  (void)bk;

  char* ws = (char*)d_ws;
  _Float16*      th16  = (_Float16*)(ws);                    // 33,554,432
  _Float16*      tl16  = (_Float16*)(ws + 33554432);         // 33,554,432
  _Float16*      vbf   = (_Float16*)(ws + 67108864);         // 33,554,432
  float*         sc    = (float*)(ws + 100663296);           // 68,157,440
  _Float16*      ph16  = (_Float16*)(ws + 168820736);        // 589,824
  _Float16*      pl16  = (_Float16*)(ws + 169410560);        // 589,824
  _Float16*      wvt16 = (_Float16*)(ws + 170000384);        // 524,288
  float*         qb    = (float*)(ws + 170524672);           // 133,120
  float*         yb    = (float*)(ws + 170657792);           // 4,259,840
  float*         zb    = (float*)(ws + 174917632);           // 4,259,840
  unsigned int*  mm    = (unsigned int*)(ws + 179177472);    // 8
  float2*        wmm   = (float2*)(ws + 179177488);          // 133,120

  hipMemsetAsync(mm, 0xFF, 4, stream);
  hipMemsetAsync((char*)mm + 4, 0x00, 4, stream);

  transform_split_kernel<<<2048, 256, 0, stream>>>(x, th16, tl16, B_ * L_ * D_ / 4);
  wvt_kernel<<<512, 256, 0, stream>>>(Wv, wvt16);
  qproj_kernel<<<dim3(G_, 2), 256, 0, stream>>>(target, Wq, bq, qb);
  p_kernel<<<HGP_, 256, 0, stream>>>(qb, Wk, ph16, pl16);
  scores_gemm_kernel<<<dim3(256, 6), 256, 0, stream>>>(th16, tl16, ph16, pl16, sc);
  vgemm_kernel<<<dim3(256, 4), 256, 0, stream>>>(th16, wvt16, bv, vbf);
  topk_conv_kernel<<<NROW_ / 4, 256, 0, stream>>>(sc, vbf, conv_w, conv_b, yb, wmm);
  minmax_reduce_kernel<<<NROW_ / 256, 256, 0, stream>>>(wmm, mm);
  zprep_kernel<<<B_ * H_ * G_ * DH_ / 256, 256, 0, stream>>>(yb, mm, zb);
  out_gemm_kernel<<<dim3(8, 17), 256, 0, stream>>>(zb, Wo, bo, out);
}

// Round 12
// 405.200 us; speedup vs baseline: 1.2237x; 1.2237x over previous
//
#include <hip/hip_runtime.h>
#include <math.h>

#define B_  32
#define L_  1024
#define D_  512
#define H_  8
#define G_  65
#define K_  16
#define DH_ 64
#define HG_  (H_ * G_)   // 520
#define HGP_ 576         // padded rows for p
#define BL_  (B_ * L_)   // 32768
#define NROW_ (B_ * H_ * G_)  // 16640
#define M_OUT_ (B_ * G_)      // 2080

typedef _Float16 f16x8 __attribute__((ext_vector_type(8)));
typedef float f32x4 __attribute__((ext_vector_type(4)));

__device__ __forceinline__ unsigned int f2s(float f) {
  unsigned int u = __float_as_uint(f);
  return (u & 0x80000000u) ? ~u : (u | 0x80000000u);
}
__device__ __forceinline__ float s2f(unsigned int u) {
  return __uint_as_float((u & 0x80000000u) ? (u & 0x7FFFFFFFu) : ~u);
}
// fp16 2-plane split, flush-safe: both planes are normal-or-zero fp16 (lo is
// pre-scaled by 2^12). value ~= hi + lo*2^-12 with rel err ~2^-24.
__device__ __forceinline__ void split16(float v, _Float16* h, _Float16* l) {
  _Float16 h0 = (_Float16)v;
  float hf = (float)h0;
  if (fabsf(v) < 6.103515625e-05f) { h0 = (_Float16)0.f; hf = 0.f; }
  *h = h0;
  *l = (_Float16)((v - hf) * 4096.0f);
}
__device__ __forceinline__ void gload16(const void* g, void* l) {
  __builtin_amdgcn_global_load_lds(
      (const __attribute__((address_space(1))) unsigned int*)g,
      (__attribute__((address_space(3))) unsigned int*)l, 16, 0, 0);
}

// 1) t = log(relu(x)+1) -> fp16 hi + fp16 scaled-lo
__global__ void transform_split_kernel(const float* __restrict__ x,
                                       _Float16* __restrict__ th16,
                                       _Float16* __restrict__ tl16, int n4) {
  int i = blockIdx.x * blockDim.x + threadIdx.x;
  int stride = gridDim.x * blockDim.x;
  const float4* x4 = (const float4*)x;
  for (; i < n4; i += stride) {
    float4 a = x4[i];
    float t[4];
    t[0] = logf(fmaxf(a.x, 0.f) + 1.f);
    t[1] = logf(fmaxf(a.y, 0.f) + 1.f);
    t[2] = logf(fmaxf(a.z, 0.f) + 1.f);
    t[3] = logf(fmaxf(a.w, 0.f) + 1.f);
    _Float16 h[4], l[4];
#pragma unroll
    for (int j = 0; j < 4; ++j) split16(t[j], &h[j], &l[j]);
    *(ushort4*)&th16[i * 4] = *(ushort4*)h;
    *(ushort4*)&tl16[i * 4] = *(ushort4*)l;
  }
}

// 2) Wv,Wo -> transposed fp16 (v/out paths are precision-insensitive)
__global__ __launch_bounds__(256) void wprep_kernel(const float* __restrict__ Wv,
                                                    const float* __restrict__ Wo,
                                                    _Float16* __restrict__ wvt16,
                                                    _Float16* __restrict__ wot16) {
  int n = blockIdx.x;
  for (int k = threadIdx.x; k < 512; k += 256) {
    wvt16[n * 512 + k] = (_Float16)Wv[(size_t)k * 512 + n];
    wot16[n * 512 + k] = (_Float16)Wo[(size_t)k * 512 + n];
  }
}

// 3) q = target @ Wq + bq   [G,512] fp32
__global__ __launch_bounds__(256) void qproj_kernel(const float* __restrict__ target,
                                                    const float* __restrict__ Wq,
                                                    const float* __restrict__ bq,
                                                    float* __restrict__ q) {
  int g = blockIdx.x;
  int d = blockIdx.y * 256 + threadIdx.x;
  __shared__ float ts[512];
  for (int i = threadIdx.x; i < 512; i += 256) ts[i] = target[g * 512 + i];
  __syncthreads();
  float acc = bq[d];
  for (int c = 0; c < 512; ++c) acc += ts[c] * Wq[c * 512 + d];
  q[g * 512 + d] = acc;
}

// 4) p[hg][c] = sum_d Wk[c][h*64+d] * q[g][h*64+d], fp32 -> fp16 hi/lo planes.
//    rows 520..575 zeroed.
__global__ __launch_bounds__(256) void p_kernel(const float* __restrict__ q,
                                                const float* __restrict__ Wk,
                                                _Float16* __restrict__ ph16,
                                                _Float16* __restrict__ pl16) {
  int hg = blockIdx.x;
  int tid = threadIdx.x;
  if (hg >= HG_) {
    ph16[(size_t)hg * 512 + tid] = (_Float16)0.f;
    ph16[(size_t)hg * 512 + tid + 256] = (_Float16)0.f;
    pl16[(size_t)hg * 512 + tid] = (_Float16)0.f;
    pl16[(size_t)hg * 512 + tid + 256] = (_Float16)0.f;
    return;
  }
  int h = hg / G_, g = hg % G_;
  int lane = tid & 63, wid = tid >> 6;
  float qv = q[g * 512 + h * 64 + lane];
  for (int c = wid * 128; c < wid * 128 + 128; ++c) {
    float prod = Wk[(size_t)c * 512 + h * 64 + lane] * qv;
#pragma unroll
    for (int off = 32; off > 0; off >>= 1) prod += __shfl_xor(prod, off);
    if (lane == 0) {
      _Float16 hh, ll;
      split16(prod, &hh, &ll);
      ph16[(size_t)hg * 512 + c] = hh;
      pl16[(size_t)hg * 512 + c] = ll;
    }
  }
}

// 5) scores GEMM: S = p . t, fp16 2-plane / 3-product (rel err ~2^-24).
//    r10-proven structure: double-buffered BK=32 one-barrier pipeline,
//    (256,2). STAGE issued FIRST in each k-step (max load flight time).
//    M-tile 96 (grid.y=6), N-tile 128 (grid.x=256).
__global__ __launch_bounds__(256, 2) void scores_gemm_kernel(
    const _Float16* __restrict__ th16, const _Float16* __restrict__ tl16,
    const _Float16* __restrict__ ph16, const _Float16* __restrict__ pl16,
    float* __restrict__ scores) {
  // 2 bufs x 2 planes x [128 rows][32 k] fp16 = 2 x 16KB
  __shared__ char lds[32768];
  const int tid = threadIdx.x;
  const int lane = tid & 63;
  const int wid = tid >> 6;          // wave 0..3 -> n-subtile of 32 cols
  const int n0 = blockIdx.x * 128;
  const int m0 = blockIdx.y * 96;
  const int l16 = lane & 15;
  const int lg = lane >> 4;          // k-group 0..3 (8 elems each)

  f32x4 acc0[6][2], acc1[6][2];
#pragma unroll
  for (int i = 0; i < 6; ++i)
#pragma unroll
    for (int j = 0; j < 2; ++j) { acc0[i][j] = (f32x4)(0.f); acc1[i][j] = (f32x4)(0.f); }

  const int st_row = wid * 16 + (lane >> 2);
  const int st_s   = lane & 3;

#define STAGE_SC(buf, ks)                                                      \
  {                                                                            \
    _Pragma("unroll")                                                          \
    for (int it = 0; it < 2; ++it) {                                           \
      int row = it * 64 + st_row;                                              \
      size_t src = (size_t)(n0 + row) * 512 + (ks) * 32 +                      \
                   ((st_s ^ (row & 3)) << 3);                                  \
      char* dst = lds + (buf) * 16384 + it * 4096 + wid * 1024;                \
      gload16(th16 + src, dst);                                                \
      gload16(tl16 + src, dst + 8192);                                         \
    }                                                                          \
  }

  const size_t arow = (size_t)(m0 + l16) * 512 + lg * 8;

  STAGE_SC(0, 0);
  __syncthreads();

  for (int ks = 0; ks < 16; ++ks) {
    const int cur = ks & 1;
    // issue next-tile staging FIRST: max flight time before the end barrier
    if (ks < 15) STAGE_SC(cur ^ 1, ks + 1);
    // A fragments (p planes, L2-resident)
    f16x8 Ah[6], Al[6];
#pragma unroll
    for (int fm = 0; fm < 6; ++fm) {
      size_t ao = arow + (size_t)fm * 16 * 512 + ks * 32;
      Ah[fm] = *(const f16x8*)(ph16 + ao);
      Al[fm] = *(const f16x8*)(pl16 + ao);
    }
    // B fragments from current LDS buffer
    f16x8 Bh[2], Bl[2];
#pragma unroll
    for (int fn = 0; fn < 2; ++fn) {
      int r = wid * 32 + fn * 16 + l16;
      int addr = cur * 16384 + r * 64 + ((lg ^ (r & 3)) << 4);
      Bh[fn] = *(const f16x8*)(lds + addr);
      Bl[fn] = *(const f16x8*)(lds + addr + 8192);
    }
#pragma unroll
    for (int fm = 0; fm < 6; ++fm) {
#pragma unroll
      for (int fn = 0; fn < 2; ++fn) {
        acc0[fm][fn] = __builtin_amdgcn_mfma_f32_16x16x32_f16(Ah[fm], Bh[fn], acc0[fm][fn], 0, 0, 0);
        acc1[fm][fn] = __builtin_amdgcn_mfma_f32_16x16x32_f16(Ah[fm], Bl[fn], acc1[fm][fn], 0, 0, 0);
        acc1[fm][fn] = __builtin_amdgcn_mfma_f32_16x16x32_f16(Al[fm], Bh[fn], acc1[fm][fn], 0, 0, 0);
      }
    }
    __syncthreads();
  }
#undef STAGE_SC

#pragma unroll
  for (int fm = 0; fm < 6; ++fm) {
    int hg0 = m0 + fm * 16 + ((lane >> 4) << 2);
#pragma unroll
    for (int fn = 0; fn < 2; ++fn) {
      int col = n0 + wid * 32 + fn * 16 + l16;
#pragma unroll
      for (int r = 0; r < 4; ++r) {
        int row = hg0 + r;
        if (row < HG_)
          scores[(size_t)row * BL_ + col] =
              acc0[fm][fn][r] + acc1[fm][fn][r] * 0.000244140625f;
      }
    }
  }
}

// 6) V GEMM: V[bl][n] = sum_c t[bl][c]*Wv[c][n] + bv[n], fp16 1-term
//    (v path precision-insensitive: r3/r4 bit-identical absmax evidence).
//    fp16 output. M-tile 128 (grid.x=256), N-tile 128 (grid.y=4).
__global__ __launch_bounds__(256, 2) void vgemm_kernel(
    const _Float16* __restrict__ th16, const _Float16* __restrict__ wvt16,
    const float* __restrict__ bv, _Float16* __restrict__ vout) {
  __shared__ char lds[16384];  // t_hi tile [128][64] fp16, slot-swizzled
  const int tid = threadIdx.x;
  const int lane = tid & 63;
  const int wid = tid >> 6;
  const int wave_m = wid >> 1;
  const int wave_n = wid & 1;
  const int m0 = blockIdx.x * 128;
  const int n0 = blockIdx.y * 128;

  f32x4 acc[4][4];
#pragma unroll
  for (int i = 0; i < 4; ++i)
#pragma unroll
    for (int j = 0; j < 4; ++j) acc[i][j] = (f32x4)(0.f);

  for (int k0 = 0; k0 < 512; k0 += 64) {
#pragma unroll
    for (int it = 0; it < 4; ++it) {
      int row = it * 32 + (tid >> 3);
      int j = tid & 7;
      size_t src = (size_t)(m0 + row) * 512 + k0 + ((j ^ (row & 7)) << 3);
      gload16(th16 + src, lds + it * 4096 + wid * 1024);
    }
    __syncthreads();
#pragma unroll
    for (int kh = 0; kh < 2; ++kh) {
      f16x8 Bv[4];
#pragma unroll
      for (int fn = 0; fn < 4; ++fn) {
        size_t bo = (size_t)(n0 + wave_n * 64 + fn * 16 + (lane & 15)) * 512 + k0 +
                    kh * 32 + ((lane >> 4) << 3);
        Bv[fn] = *(const f16x8*)(wvt16 + bo);
      }
#pragma unroll
      for (int fm = 0; fm < 4; ++fm) {
        int r = wave_m * 64 + fm * 16 + (lane & 15);
        int jl = kh * 4 + (lane >> 4);
        f16x8 Af = *(const f16x8*)(lds + r * 128 + ((jl ^ (r & 7)) << 4));
#pragma unroll
        for (int fn = 0; fn < 4; ++fn)
          acc[fm][fn] = __builtin_amdgcn_mfma_f32_16x16x32_f16(Af, Bv[fn], acc[fm][fn], 0, 0, 0);
      }
    }
    __syncthreads();
  }
#pragma unroll
  for (int fm = 0; fm < 4; ++fm) {
#pragma unroll
    for (int fn = 0; fn < 4; ++fn) {
      int col = n0 + wave_n * 64 + fn * 16 + (lane & 15);
      float bvv = bv[col];
#pragma unroll
      for (int r = 0; r < 4; ++r) {
        int row = m0 + wave_m * 64 + fm * 16 + ((lane >> 4) << 2) + r;
        vout[(size_t)row * 512 + col] = (_Float16)(acc[fm][fn][r] + bvv);
      }
    }
  }
}

// 7) one WAVE per row: top-16 with FUSED conv gather (v fp16); per-row
//    (min,max) to wmm[row] (no contended atomics).
__global__ __launch_bounds__(256) void topk_conv_kernel(const float* __restrict__ scores,
                                                        const _Float16* __restrict__ vbuf,
                                                        const float* __restrict__ conv_w,
                                                        const float* __restrict__ conv_b,
                                                        float* __restrict__ y,
                                                        float2* __restrict__ wmm) {
  int row = blockIdx.x * 4 + (threadIdx.x >> 6);  // (b*8+h)*65 + g
  int lane = threadIdx.x & 63;
  int g = row % G_;
  int bh = row / G_;
  int b = bh >> 3, h = bh & 7;
  const float* srow = scores + (size_t)(h * G_ + g) * BL_ + b * 1024;

  float s[16];
#pragma unroll
  for (int j = 0; j < 16; ++j) s[j] = srow[j * 64 + lane];  // coalesced

  const _Float16* vrow = vbuf + (size_t)b * 1024 * 512 + h * 64 + lane;
  float acc = conv_b[g];

#pragma unroll
  for (int r = 0; r < 16; ++r) {
    float bs = s[0];
    int bl = lane;
#pragma unroll
    for (int j = 1; j < 16; ++j) {
      bool t = s[j] > bs;
      bs = t ? s[j] : bs;
      bl = t ? j * 64 + lane : bl;
    }
#pragma unroll
    for (int off = 32; off > 0; off >>= 1) {
      float os = __shfl_xor(bs, off);
      int ol = __shfl_xor(bl, off);
      bool take = (os > bs) || (os == bs && ol < bl);
      bs = take ? os : bs;
      bl = take ? ol : bl;
    }
#pragma unroll
    for (int j = 0; j < 16; ++j)
      if (bl == j * 64 + lane) s[j] = -INFINITY;
    int sl = __builtin_amdgcn_readfirstlane(bl);
    acc += conv_w[g * 16 + r] * (float)vrow[(size_t)sl * 512];
  }

  y[(size_t)row * 64 + lane] = acc;

  float mn = acc, mx = acc;
#pragma unroll
  for (int off = 32; off > 0; off >>= 1) {
    float o = __shfl_xor(mn, off); mn = fminf(mn, o);
    float p = __shfl_xor(mx, off); mx = fmaxf(mx, p);
  }
  if (lane == 0) wmm[row] = make_float2(mn, mx);
}

// 7b) reduce 16640 per-row (min,max) pairs -> mm (130 uncontended atomics)
__global__ __launch_bounds__(256) void minmax_reduce_kernel(const float2* __restrict__ wmm,
                                                            unsigned int* __restrict__ minmax) {
  int i = blockIdx.x * 256 + threadIdx.x;
  float2 v = wmm[i];
  float mn = v.x, mx = v.y;
#pragma unroll
  for (int off = 32; off > 0; off >>= 1) {
    float o = __shfl_xor(mn, off); mn = fminf(mn, o);
    float p = __shfl_xor(mx, off); mx = fmaxf(mx, p);
  }
  __shared__ float smn[4], smx[4];
  int lane = threadIdx.x & 63, wid = threadIdx.x >> 6;
  if (lane == 0) { smn[wid] = mn; smx[wid] = mx; }
  __syncthreads();
  if (threadIdx.x == 0) {
    mn = fminf(fminf(smn[0], smn[1]), fminf(smn[2], smn[3]));
    mx = fmaxf(fmaxf(smx[0], smx[1]), fmaxf(smx[2], smx[3]));
    atomicMin(&minmax[0], f2s(mn));
    atomicMax(&minmax[1], f2s(mx));
  }
}

// 8) z16[b*65+g][h*64+c] = fp16(exp((y[b,h,g,c]-mn)/(mx-mn)))
//    (z in [1,e]; fp16 rel 5e-4 -> out err ~3e-3 vs 0.12 threshold)
__global__ void zprep_kernel(const float* __restrict__ y,
                             const unsigned int* __restrict__ minmax,
                             _Float16* __restrict__ z16) {
  int i = blockIdx.x * 256 + threadIdx.x;
  float mn = s2f(minmax[0]);
  float mx = s2f(minmax[1]);
  float inv = 1.f / (mx - mn);
  int c = i & 63;
  int t = i >> 6;
  int g = t % G_;
  int bh = t / G_;
  int b = bh >> 3, h = bh & 7;
  z16[(size_t)(b * G_ + g) * 512 + h * 64 + c] = (_Float16)expf((y[i] - mn) * inv);
}

// 9) out = z @ Wo + bo ; fp16 1-term MFMA (vgemm clone, M=2080 guarded).
//    grid (17, 4): m-tiles 128 (last clamped), n-tiles 128.
__global__ __launch_bounds__(256, 2) void out_gemm_kernel(
    const _Float16* __restrict__ z16, const _Float16* __restrict__ wot16,
    const float* __restrict__ bo, float* __restrict__ out) {
  __shared__ char lds[16384];  // z tile [128][64] fp16, slot-swizzled
  const int tid = threadIdx.x;
  const int lane = tid & 63;
  const int wid = tid >> 6;
  const int wave_m = wid >> 1;
  const int wave_n = wid & 1;
  const int m0 = blockIdx.x * 128;
  const int n0 = blockIdx.y * 128;

  f32x4 acc[4][4];
#pragma unroll
  for (int i = 0; i < 4; ++i)
#pragma unroll
    for (int j = 0; j < 4; ++j) acc[i][j] = (f32x4)(0.f);

  for (int k0 = 0; k0 < 512; k0 += 64) {
#pragma unroll
    for (int it = 0; it < 4; ++it) {
      int row = it * 32 + (tid >> 3);
      int grow = m0 + row;
      if (grow > M_OUT_ - 1) grow = M_OUT_ - 1;  // clamp (stays in-bounds)
      int j = tid & 7;
      size_t src = (size_t)grow * 512 + k0 + ((j ^ (row & 7)) << 3);
      gload16(z16 + src, lds + it * 4096 + wid * 1024);
    }
    __syncthreads();
#pragma unroll
    for (int kh = 0; kh < 2; ++kh) {
      f16x8 Bw[4];
#pragma unroll
      for (int fn = 0; fn < 4; ++fn) {
        size_t bo_off = (size_t)(n0 + wave_n * 64 + fn * 16 + (lane & 15)) * 512 +
                        k0 + kh * 32 + ((lane >> 4) << 3);
        Bw[fn] = *(const f16x8*)(wot16 + bo_off);
      }
#pragma unroll
      for (int fm = 0; fm < 4; ++fm) {
        int r = wave_m * 64 + fm * 16 + (lane & 15);
        int jl = kh * 4 + (lane >> 4);
        f16x8 Af = *(const f16x8*)(lds + r * 128 + ((jl ^ (r & 7)) << 4));
#pragma unroll
        for (int fn = 0; fn < 4; ++fn)
          acc[fm][fn] = __builtin_amdgcn_mfma_f32_16x16x32_f16(Af, Bw[fn], acc[fm][fn], 0, 0, 0);
      }
    }
    __syncthreads();
  }
#pragma unroll
  for (int fm = 0; fm < 4; ++fm) {
#pragma unroll
    for (int fn = 0; fn < 4; ++fn) {
      int col = n0 + wave_n * 64 + fn * 16 + (lane & 15);
      float bov = bo[col];
#pragma unroll
      for (int r = 0; r < 4; ++r) {
        int row = m0 + wave_m * 64 + fm * 16 + ((lane >> 4) << 2) + r;
        if (row < M_OUT_)
          out[(size_t)row * 512 + col] = acc[fm][fn][r] + bov;
      }
    }
  }
}

extern "C" void kernel_launch(void* const* d_in, const int* in_sizes, int n_in,
                              void* d_out, int out_size, void* d_ws, size_t ws_size,
                              hipStream_t stream) {
  const float* x      = (const float*)d_in[0];
  const float* Wq     = (const float*)d_in[1];
  const float* bq     = (const float*)d_in[2];
  const float* Wk     = (const float*)d_in[3];
  const float* bk     = (const float*)d_in[4];
  const float* Wv     = (const float*)d_in[5];
  const float* bv     = (const float*)d_in[6];
  const float* Wo     = (const float*)d_in[7];
  const float* bo     = (const float*)d_in[8];
  const float* target = (const float*)d_in[9];
  const float* conv_w = (const float*)d_in[10];
  const float* conv_b = (const float*)d_in[11];
  float* out = (float*)d_out;
  (void)bk;

  char* ws = (char*)d_ws;
  _Float16*      th16  = (_Float16*)(ws);                    // 33,554,432
  _Float16*      tl16  = (_Float16*)(ws + 33554432);         // 33,554,432
  _Float16*      vbf   = (_Float16*)(ws + 67108864);         // 33,554,432
  float*         sc    = (float*)(ws + 100663296);           // 68,157,440
  _Float16*      ph16  = (_Float16*)(ws + 168820736);        // 589,824
  _Float16*      pl16  = (_Float16*)(ws + 169410560);        // 589,824
  _Float16*      wvt16 = (_Float16*)(ws + 170000384);        // 524,288
  _Float16*      wot16 = (_Float16*)(ws + 170524672);        // 524,288
  float*         qb    = (float*)(ws + 171048960);           // 133,120
  float*         yb    = (float*)(ws + 171182080);           // 4,259,840
  _Float16*      z16   = (_Float16*)(ws + 175441920);        // 2,129,920
  unsigned int*  mm    = (unsigned int*)(ws + 177571840);    // 8
  float2*        wmm   = (float2*)(ws + 177571856);          // 133,120

  hipMemsetAsync(mm, 0xFF, 4, stream);
  hipMemsetAsync((char*)mm + 4, 0x00, 4, stream);

  transform_split_kernel<<<2048, 256, 0, stream>>>(x, th16, tl16, B_ * L_ * D_ / 4);
  wprep_kernel<<<512, 256, 0, stream>>>(Wv, Wo, wvt16, wot16);
  qproj_kernel<<<dim3(G_, 2), 256, 0, stream>>>(target, Wq, bq, qb);
  p_kernel<<<HGP_, 256, 0, stream>>>(qb, Wk, ph16, pl16);
  scores_gemm_kernel<<<dim3(256, 6), 256, 0, stream>>>(th16, tl16, ph16, pl16, sc);
  vgemm_kernel<<<dim3(256, 4), 256, 0, stream>>>(th16, wvt16, bv, vbf);
  topk_conv_kernel<<<NROW_ / 4, 256, 0, stream>>>(sc, vbf, conv_w, conv_b, yb, wmm);
  minmax_reduce_kernel<<<NROW_ / 256, 256, 0, stream>>>(wmm, mm);
  zprep_kernel<<<B_ * H_ * G_ * DH_ / 256, 256, 0, stream>>>(yb, mm, z16);
  out_gemm_kernel<<<dim3(17, 4), 256, 0, stream>>>(z16, wot16, bo, out);
}

// Round 13
// 399.165 us; speedup vs baseline: 1.2422x; 1.0151x over previous
//
#include <hip/hip_runtime.h>
#include <math.h>

#define B_  32
#define L_  1024
#define D_  512
#define H_  8
#define G_  65
#define K_  16
#define DH_ 64
#define HG_  (H_ * G_)   // 520
#define HGP_ 576         // padded rows for p
#define BL_  (B_ * L_)   // 32768
#define NROW_ (B_ * H_ * G_)  // 16640
#define M_OUT_ (B_ * G_)      // 2080

typedef _Float16 f16x8 __attribute__((ext_vector_type(8)));
typedef float f32x4 __attribute__((ext_vector_type(4)));

__device__ __forceinline__ unsigned int f2s(float f) {
  unsigned int u = __float_as_uint(f);
  return (u & 0x80000000u) ? ~u : (u | 0x80000000u);
}
__device__ __forceinline__ float s2f(unsigned int u) {
  return __uint_as_float((u & 0x80000000u) ? (u & 0x7FFFFFFFu) : ~u);
}
// fp16 2-plane split, flush-safe: both planes are normal-or-zero fp16 (lo is
// pre-scaled by 2^12). value ~= hi + lo*2^-12 with rel err ~2^-24.
__device__ __forceinline__ void split16(float v, _Float16* h, _Float16* l) {
  _Float16 h0 = (_Float16)v;
  float hf = (float)h0;
  if (fabsf(v) < 6.103515625e-05f) { h0 = (_Float16)0.f; hf = 0.f; }
  *h = h0;
  *l = (_Float16)((v - hf) * 4096.0f);
}
__device__ __forceinline__ void gload16(const void* g, void* l) {
  __builtin_amdgcn_global_load_lds(
      (const __attribute__((address_space(1))) unsigned int*)g,
      (__attribute__((address_space(3))) unsigned int*)l, 16, 0, 0);
}

// 1) t = log(relu(x)+1) -> fp16 hi + fp16 scaled-lo
__global__ void transform_split_kernel(const float* __restrict__ x,
                                       _Float16* __restrict__ th16,
                                       _Float16* __restrict__ tl16, int n4) {
  int i = blockIdx.x * blockDim.x + threadIdx.x;
  int stride = gridDim.x * blockDim.x;
  const float4* x4 = (const float4*)x;
  for (; i < n4; i += stride) {
    float4 a = x4[i];
    float t[4];
    t[0] = logf(fmaxf(a.x, 0.f) + 1.f);
    t[1] = logf(fmaxf(a.y, 0.f) + 1.f);
    t[2] = logf(fmaxf(a.z, 0.f) + 1.f);
    t[3] = logf(fmaxf(a.w, 0.f) + 1.f);
    _Float16 h[4], l[4];
#pragma unroll
    for (int j = 0; j < 4; ++j) split16(t[j], &h[j], &l[j]);
    *(ushort4*)&th16[i * 4] = *(ushort4*)h;
    *(ushort4*)&tl16[i * 4] = *(ushort4*)l;
  }
}

// 2) Wv,Wo -> transposed fp16 (v/out paths are precision-insensitive)
__global__ __launch_bounds__(256) void wprep_kernel(const float* __restrict__ Wv,
                                                    const float* __restrict__ Wo,
                                                    _Float16* __restrict__ wvt16,
                                                    _Float16* __restrict__ wot16) {
  int n = blockIdx.x;
  for (int k = threadIdx.x; k < 512; k += 256) {
    wvt16[n * 512 + k] = (_Float16)Wv[(size_t)k * 512 + n];
    wot16[n * 512 + k] = (_Float16)Wo[(size_t)k * 512 + n];
  }
}

// 3) q = target @ Wq + bq   [G,512] fp32
__global__ __launch_bounds__(256) void qproj_kernel(const float* __restrict__ target,
                                                    const float* __restrict__ Wq,
                                                    const float* __restrict__ bq,
                                                    float* __restrict__ q) {
  int g = blockIdx.x;
  int d = blockIdx.y * 256 + threadIdx.x;
  __shared__ float ts[512];
  for (int i = threadIdx.x; i < 512; i += 256) ts[i] = target[g * 512 + i];
  __syncthreads();
  float acc = bq[d];
  for (int c = 0; c < 512; ++c) acc += ts[c] * Wq[c * 512 + d];
  q[g * 512 + d] = acc;
}

// 4) p[hg][c] = sum_d Wk[c][h*64+d] * q[g][h*64+d], fp32 -> fp16 hi/lo planes.
//    rows 520..575 zeroed.
__global__ __launch_bounds__(256) void p_kernel(const float* __restrict__ q,
                                                const float* __restrict__ Wk,
                                                _Float16* __restrict__ ph16,
                                                _Float16* __restrict__ pl16) {
  int hg = blockIdx.x;
  int tid = threadIdx.x;
  if (hg >= HG_) {
    ph16[(size_t)hg * 512 + tid] = (_Float16)0.f;
    ph16[(size_t)hg * 512 + tid + 256] = (_Float16)0.f;
    pl16[(size_t)hg * 512 + tid] = (_Float16)0.f;
    pl16[(size_t)hg * 512 + tid + 256] = (_Float16)0.f;
    return;
  }
  int h = hg / G_, g = hg % G_;
  int lane = tid & 63, wid = tid >> 6;
  float qv = q[g * 512 + h * 64 + lane];
  for (int c = wid * 128; c < wid * 128 + 128; ++c) {
    float prod = Wk[(size_t)c * 512 + h * 64 + lane] * qv;
#pragma unroll
    for (int off = 32; off > 0; off >>= 1) prod += __shfl_xor(prod, off);
    if (lane == 0) {
      _Float16 hh, ll;
      split16(prod, &hh, &ll);
      ph16[(size_t)hg * 512 + c] = hh;
      pl16[(size_t)hg * 512 + c] = ll;
    }
  }
}

// 5) scores GEMM: S = p . t, fp16 2-plane / 3-product (rel err ~2^-24).
//    r10-proven double-buffered BK=32 one-barrier pipeline, (256,2).
//    XCD-AWARE SWIZZLE (T1): the 6 m-blocks sharing one n-tile (same t tile)
//    are placed on the SAME XCD so t is fetched from L3 once per XCD and
//    served 6x from that XCD's private L2. r10/r12 evidence: kernel is
//    L3-BW-bound (~2.5 TB/s at 402MB staged); swizzle cuts L3 traffic 6x.
//    grid = flat 1536 = 8 XCDs x 192; decode x=w&7, j=w>>3.
__global__ __launch_bounds__(256, 2) void scores_gemm_kernel(
    const _Float16* __restrict__ th16, const _Float16* __restrict__ tl16,
    const _Float16* __restrict__ ph16, const _Float16* __restrict__ pl16,
    float* __restrict__ scores) {
  // 2 bufs x 2 planes x [128 rows][32 k] fp16 = 2 x 16KB
  __shared__ char lds[32768];
  const int w = blockIdx.x;
  const int xcd = w & 7;          // dispatch round-robins w%8 across XCDs
  const int j = w >> 3;           // 0..191 within XCD
  const int n0 = (xcd * 32 + j / 6) * 128;  // n-tile 0..255
  const int m0 = (j % 6) * 96;              // m-tile 0..5
  const int tid = threadIdx.x;
  const int lane = tid & 63;
  const int wid = tid >> 6;          // wave 0..3 -> n-subtile of 32 cols
  const int l16 = lane & 15;
  const int lg = lane >> 4;          // k-group 0..3 (8 elems each)

  f32x4 acc0[6][2], acc1[6][2];
#pragma unroll
  for (int i = 0; i < 6; ++i)
#pragma unroll
    for (int jj = 0; jj < 2; ++jj) { acc0[i][jj] = (f32x4)(0.f); acc1[i][jj] = (f32x4)(0.f); }

  const int st_row = wid * 16 + (lane >> 2);
  const int st_s   = lane & 3;

#define STAGE_SC(buf, ks)                                                      \
  {                                                                            \
    _Pragma("unroll")                                                          \
    for (int it = 0; it < 2; ++it) {                                           \
      int row = it * 64 + st_row;                                              \
      size_t src = (size_t)(n0 + row) * 512 + (ks) * 32 +                      \
                   ((st_s ^ (row & 3)) << 3);                                  \
      char* dst = lds + (buf) * 16384 + it * 4096 + wid * 1024;                \
      gload16(th16 + src, dst);                                                \
      gload16(tl16 + src, dst + 8192);                                         \
    }                                                                          \
  }

  const size_t arow = (size_t)(m0 + l16) * 512 + lg * 8;

  STAGE_SC(0, 0);
  __syncthreads();

  for (int ks = 0; ks < 16; ++ks) {
    const int cur = ks & 1;
    if (ks < 15) STAGE_SC(cur ^ 1, ks + 1);
    // A fragments (p planes, L2-resident)
    f16x8 Ah[6], Al[6];
#pragma unroll
    for (int fm = 0; fm < 6; ++fm) {
      size_t ao = arow + (size_t)fm * 16 * 512 + ks * 32;
      Ah[fm] = *(const f16x8*)(ph16 + ao);
      Al[fm] = *(const f16x8*)(pl16 + ao);
    }
    // B fragments from current LDS buffer
    f16x8 Bh[2], Bl[2];
#pragma unroll
    for (int fn = 0; fn < 2; ++fn) {
      int r = wid * 32 + fn * 16 + l16;
      int addr = cur * 16384 + r * 64 + ((lg ^ (r & 3)) << 4);
      Bh[fn] = *(const f16x8*)(lds + addr);
      Bl[fn] = *(const f16x8*)(lds + addr + 8192);
    }
#pragma unroll
    for (int fm = 0; fm < 6; ++fm) {
#pragma unroll
      for (int fn = 0; fn < 2; ++fn) {
        acc0[fm][fn] = __builtin_amdgcn_mfma_f32_16x16x32_f16(Ah[fm], Bh[fn], acc0[fm][fn], 0, 0, 0);
        acc1[fm][fn] = __builtin_amdgcn_mfma_f32_16x16x32_f16(Ah[fm], Bl[fn], acc1[fm][fn], 0, 0, 0);
        acc1[fm][fn] = __builtin_amdgcn_mfma_f32_16x16x32_f16(Al[fm], Bh[fn], acc1[fm][fn], 0, 0, 0);
      }
    }
    __syncthreads();
  }
#undef STAGE_SC

#pragma unroll
  for (int fm = 0; fm < 6; ++fm) {
    int hg0 = m0 + fm * 16 + ((lane >> 4) << 2);
#pragma unroll
    for (int fn = 0; fn < 2; ++fn) {
      int col = n0 + wid * 32 + fn * 16 + l16;
#pragma unroll
      for (int r = 0; r < 4; ++r) {
        int row = hg0 + r;
        if (row < HG_)
          scores[(size_t)row * BL_ + col] =
              acc0[fm][fn][r] + acc1[fm][fn][r] * 0.000244140625f;
      }
    }
  }
}

// 6) V GEMM: V[bl][n] = sum_c t[bl][c]*Wv[c][n] + bv[n], fp16 1-term
//    (v path precision-insensitive: r3/r4 bit-identical absmax evidence).
//    fp16 output. M-tile 128 (grid.x=256), N-tile 128 (grid.y=4).
__global__ __launch_bounds__(256, 2) void vgemm_kernel(
    const _Float16* __restrict__ th16, const _Float16* __restrict__ wvt16,
    const float* __restrict__ bv, _Float16* __restrict__ vout) {
  __shared__ char lds[16384];  // t_hi tile [128][64] fp16, slot-swizzled
  const int tid = threadIdx.x;
  const int lane = tid & 63;
  const int wid = tid >> 6;
  const int wave_m = wid >> 1;
  const int wave_n = wid & 1;
  const int m0 = blockIdx.x * 128;
  const int n0 = blockIdx.y * 128;

  f32x4 acc[4][4];
#pragma unroll
  for (int i = 0; i < 4; ++i)
#pragma unroll
    for (int j = 0; j < 4; ++j) acc[i][j] = (f32x4)(0.f);

  for (int k0 = 0; k0 < 512; k0 += 64) {
#pragma unroll
    for (int it = 0; it < 4; ++it) {
      int row = it * 32 + (tid >> 3);
      int j = tid & 7;
      size_t src = (size_t)(m0 + row) * 512 + k0 + ((j ^ (row & 7)) << 3);
      gload16(th16 + src, lds + it * 4096 + wid * 1024);
    }
    __syncthreads();
#pragma unroll
    for (int kh = 0; kh < 2; ++kh) {
      f16x8 Bv[4];
#pragma unroll
      for (int fn = 0; fn < 4; ++fn) {
        size_t bo = (size_t)(n0 + wave_n * 64 + fn * 16 + (lane & 15)) * 512 + k0 +
                    kh * 32 + ((lane >> 4) << 3);
        Bv[fn] = *(const f16x8*)(wvt16 + bo);
      }
#pragma unroll
      for (int fm = 0; fm < 4; ++fm) {
        int r = wave_m * 64 + fm * 16 + (lane & 15);
        int jl = kh * 4 + (lane >> 4);
        f16x8 Af = *(const f16x8*)(lds + r * 128 + ((jl ^ (r & 7)) << 4));
#pragma unroll
        for (int fn = 0; fn < 4; ++fn)
          acc[fm][fn] = __builtin_amdgcn_mfma_f32_16x16x32_f16(Af, Bv[fn], acc[fm][fn], 0, 0, 0);
      }
    }
    __syncthreads();
  }
#pragma unroll
  for (int fm = 0; fm < 4; ++fm) {
#pragma unroll
    for (int fn = 0; fn < 4; ++fn) {
      int col = n0 + wave_n * 64 + fn * 16 + (lane & 15);
      float bvv = bv[col];
#pragma unroll
      for (int r = 0; r < 4; ++r) {
        int row = m0 + wave_m * 64 + fm * 16 + ((lane >> 4) << 2) + r;
        vout[(size_t)row * 512 + col] = (_Float16)(acc[fm][fn][r] + bvv);
      }
    }
  }
}

// 7) one WAVE per row: top-16 with FUSED conv gather (v fp16); per-row
//    (min,max) to wmm[row] (no contended atomics).
__global__ __launch_bounds__(256) void topk_conv_kernel(const float* __restrict__ scores,
                                                        const _Float16* __restrict__ vbuf,
                                                        const float* __restrict__ conv_w,
                                                        const float* __restrict__ conv_b,
                                                        float* __restrict__ y,
                                                        float2* __restrict__ wmm) {
  int row = blockIdx.x * 4 + (threadIdx.x >> 6);  // (b*8+h)*65 + g
  int lane = threadIdx.x & 63;
  int g = row % G_;
  int bh = row / G_;
  int b = bh >> 3, h = bh & 7;
  const float* srow = scores + (size_t)(h * G_ + g) * BL_ + b * 1024;

  float s[16];
#pragma unroll
  for (int j = 0; j < 16; ++j) s[j] = srow[j * 64 + lane];  // coalesced

  const _Float16* vrow = vbuf + (size_t)b * 1024 * 512 + h * 64 + lane;
  float acc = conv_b[g];

#pragma unroll
  for (int r = 0; r < 16; ++r) {
    float bs = s[0];
    int bl = lane;
#pragma unroll
    for (int j = 1; j < 16; ++j) {
      bool t = s[j] > bs;
      bs = t ? s[j] : bs;
      bl = t ? j * 64 + lane : bl;
    }
#pragma unroll
    for (int off = 32; off > 0; off >>= 1) {
      float os = __shfl_xor(bs, off);
      int ol = __shfl_xor(bl, off);
      bool take = (os > bs) || (os == bs && ol < bl);
      bs = take ? os : bs;
      bl = take ? ol : bl;
    }
#pragma unroll
    for (int j = 0; j < 16; ++j)
      if (bl == j * 64 + lane) s[j] = -INFINITY;
    int sl = __builtin_amdgcn_readfirstlane(bl);
    acc += conv_w[g * 16 + r] * (float)vrow[(size_t)sl * 512];
  }

  y[(size_t)row * 64 + lane] = acc;

  float mn = acc, mx = acc;
#pragma unroll
  for (int off = 32; off > 0; off >>= 1) {
    float o = __shfl_xor(mn, off); mn = fminf(mn, o);
    float p = __shfl_xor(mx, off); mx = fmaxf(mx, p);
  }
  if (lane == 0) wmm[row] = make_float2(mn, mx);
}

// 7b) reduce 16640 per-row (min,max) pairs -> mm (130 uncontended atomics)
__global__ __launch_bounds__(256) void minmax_reduce_kernel(const float2* __restrict__ wmm,
                                                            unsigned int* __restrict__ minmax) {
  int i = blockIdx.x * 256 + threadIdx.x;
  float2 v = wmm[i];
  float mn = v.x, mx = v.y;
#pragma unroll
  for (int off = 32; off > 0; off >>= 1) {
    float o = __shfl_xor(mn, off); mn = fminf(mn, o);
    float p = __shfl_xor(mx, off); mx = fmaxf(mx, p);
  }
  __shared__ float smn[4], smx[4];
  int lane = threadIdx.x & 63, wid = threadIdx.x >> 6;
  if (lane == 0) { smn[wid] = mn; smx[wid] = mx; }
  __syncthreads();
  if (threadIdx.x == 0) {
    mn = fminf(fminf(smn[0], smn[1]), fminf(smn[2], smn[3]));
    mx = fmaxf(fmaxf(smx[0], smx[1]), fmaxf(smx[2], smx[3]));
    atomicMin(&minmax[0], f2s(mn));
    atomicMax(&minmax[1], f2s(mx));
  }
}

// 8) z16[b*65+g][h*64+c] = fp16(exp((y[b,h,g,c]-mn)/(mx-mn)))
__global__ void zprep_kernel(const float* __restrict__ y,
                             const unsigned int* __restrict__ minmax,
                             _Float16* __restrict__ z16) {
  int i = blockIdx.x * 256 + threadIdx.x;
  float mn = s2f(minmax[0]);
  float mx = s2f(minmax[1]);
  float inv = 1.f / (mx - mn);
  int c = i & 63;
  int t = i >> 6;
  int g = t % G_;
  int bh = t / G_;
  int b = bh >> 3, h = bh & 7;
  z16[(size_t)(b * G_ + g) * 512 + h * 64 + c] = (_Float16)expf((y[i] - mn) * inv);
}

// 9) out = z @ Wo + bo ; fp16 1-term MFMA (vgemm clone, M=2080 guarded).
__global__ __launch_bounds__(256, 2) void out_gemm_kernel(
    const _Float16* __restrict__ z16, const _Float16* __restrict__ wot16,
    const float* __restrict__ bo, float* __restrict__ out) {
  __shared__ char lds[16384];  // z tile [128][64] fp16, slot-swizzled
  const int tid = threadIdx.x;
  const int lane = tid & 63;
  const int wid = tid >> 6;
  const int wave_m = wid >> 1;
  const int wave_n = wid & 1;
  const int m0 = blockIdx.x * 128;
  const int n0 = blockIdx.y * 128;

  f32x4 acc[4][4];
#pragma unroll
  for (int i = 0; i < 4; ++i)
#pragma unroll
    for (int j = 0; j < 4; ++j) acc[i][j] = (f32x4)(0.f);

  for (int k0 = 0; k0 < 512; k0 += 64) {
#pragma unroll
    for (int it = 0; it < 4; ++it) {
      int row = it * 32 + (tid >> 3);
      int grow = m0 + row;
      if (grow > M_OUT_ - 1) grow = M_OUT_ - 1;  // clamp (stays in-bounds)
      int j = tid & 7;
      size_t src = (size_t)grow * 512 + k0 + ((j ^ (row & 7)) << 3);
      gload16(z16 + src, lds + it * 4096 + wid * 1024);
    }
    __syncthreads();
#pragma unroll
    for (int kh = 0; kh < 2; ++kh) {
      f16x8 Bw[4];
#pragma unroll
      for (int fn = 0; fn < 4; ++fn) {
        size_t bo_off = (size_t)(n0 + wave_n * 64 + fn * 16 + (lane & 15)) * 512 +
                        k0 + kh * 32 + ((lane >> 4) << 3);
        Bw[fn] = *(const f16x8*)(wot16 + bo_off);
      }
#pragma unroll
      for (int fm = 0; fm < 4; ++fm) {
        int r = wave_m * 64 + fm * 16 + (lane & 15);
        int jl = kh * 4 + (lane >> 4);
        f16x8 Af = *(const f16x8*)(lds + r * 128 + ((jl ^ (r & 7)) << 4));
#pragma unroll
        for (int fn = 0; fn < 4; ++fn)
          acc[fm][fn] = __builtin_amdgcn_mfma_f32_16x16x32_f16(Af, Bw[fn], acc[fm][fn], 0, 0, 0);
      }
    }
    __syncthreads();
  }
#pragma unroll
  for (int fm = 0; fm < 4; ++fm) {
#pragma unroll
    for (int fn = 0; fn < 4; ++fn) {
      int col = n0 + wave_n * 64 + fn * 16 + (lane & 15);
      float bov = bo[col];
#pragma unroll
      for (int r = 0; r < 4; ++r) {
        int row = m0 + wave_m * 64 + fm * 16 + ((lane >> 4) << 2) + r;
        if (row < M_OUT_)
          out[(size_t)row * 512 + col] = acc[fm][fn][r] + bov;
      }
    }
  }
}

extern "C" void kernel_launch(void* const* d_in, const int* in_sizes, int n_in,
                              void* d_out, int out_size, void* d_ws, size_t ws_size,
                              hipStream_t stream) {
  const float* x      = (const float*)d_in[0];
  const float* Wq     = (const float*)d_in[1];
  const float* bq     = (const float*)d_in[2];
  const float* Wk     = (const float*)d_in[3];
  const float* bk     = (const float*)d_in[4];
  const float* Wv     = (const float*)d_in[5];
  const float* bv     = (const float*)d_in[6];
  const float* Wo     = (const float*)d_in[7];
  const float* bo     = (const float*)d_in[8];
  const float* target = (const float*)d_in[9];
  const float* conv_w = (const float*)d_in[10];
  const float* conv_b = (const float*)d_in[11];
  float* out = (float*)d_out;
  (void)bk;

  char* ws = (char*)d_ws;
  _Float16*      th16  = (_Float16*)(ws);                    // 33,554,432
  _Float16*      tl16  = (_Float16*)(ws + 33554432);         // 33,554,432
  _Float16*      vbf   = (_Float16*)(ws + 67108864);         // 33,554,432
  float*         sc    = (float*)(ws + 100663296);           // 68,157,440
  _Float16*      ph16  = (_Float16*)(ws + 168820736);        // 589,824
  _Float16*      pl16  = (_Float16*)(ws + 169410560);        // 589,824
  _Float16*      wvt16 = (_Float16*)(ws + 170000384);        // 524,288
  _Float16*      wot16 = (_Float16*)(ws + 170524672);        // 524,288
  float*         qb    = (float*)(ws + 171048960);           // 133,120
  float*         yb    = (float*)(ws + 171182080);           // 4,259,840
  _Float16*      z16   = (_Float16*)(ws + 175441920);        // 2,129,920
  unsigned int*  mm    = (unsigned int*)(ws + 177571840);    // 8
  float2*        wmm   = (float2*)(ws + 177571856);          // 133,120

  hipMemsetAsync(mm, 0xFF, 4, stream);
  hipMemsetAsync((char*)mm + 4, 0x00, 4, stream);

  transform_split_kernel<<<2048, 256, 0, stream>>>(x, th16, tl16, B_ * L_ * D_ / 4);
  wprep_kernel<<<512, 256, 0, stream>>>(Wv, Wo, wvt16, wot16);
  qproj_kernel<<<dim3(G_, 2), 256, 0, stream>>>(target, Wq, bq, qb);
  p_kernel<<<HGP_, 256, 0, stream>>>(qb, Wk, ph16, pl16);
  scores_gemm_kernel<<<1536, 256, 0, stream>>>(th16, tl16, ph16, pl16, sc);
  vgemm_kernel<<<dim3(256, 4), 256, 0, stream>>>(th16, wvt16, bv, vbf);
  topk_conv_kernel<<<NROW_ / 4, 256, 0, stream>>>(sc, vbf, conv_w, conv_b, yb, wmm);
  minmax_reduce_kernel<<<NROW_ / 256, 256, 0, stream>>>(wmm, mm);
  zprep_kernel<<<B_ * H_ * G_ * DH_ / 256, 256, 0, stream>>>(yb, mm, z16);
  out_gemm_kernel<<<dim3(17, 4), 256, 0, stream>>>(z16, wot16, bo, out);
}